// Round 3
// baseline (466.780 us; speedup 1.0000x reference)
//
#include <hip/hip_runtime.h>

// B=8, N=2048, C=512. Flash attention + fp16 MFMA pipeline.
// attn: 4-wave blocks, 32 q/block (2 q-groups x 2 D-halves), 2 waves/SIMD,
// 2 barriers/key-tile, defer-max, XCD-bijective batch swizzle.
// ws layout: xb(16MB) h(16MB) l(16MB) gT(16MB) y(16MB) Wt(2MB)  [fp16 bits in short]

typedef __attribute__((ext_vector_type(4))) float f32x4;
typedef __attribute__((ext_vector_type(8))) short s16x8;      // fp16 bit-patterns
typedef __attribute__((ext_vector_type(8))) _Float16 f16x8;   // MFMA operand

__device__ __forceinline__ short f2h(float f) {
  _Float16 h = (_Float16)f;  // v_cvt_f16_f32, RTN
  return __builtin_bit_cast(short, h);
}

#define MFMA(a, b, c) __builtin_amdgcn_mfma_f32_16x16x32_f16(a, b, c, 0, 0, 0)

// ---------------- conversion kernels ----------------

__global__ __launch_bounds__(256) void conv_x_kernel(const float* __restrict__ x,
                                                     short* __restrict__ xb) {
  int i = blockIdx.x * 256 + threadIdx.x;
  const float4* xv = (const float4*)x;
  float4 a = xv[2 * i], b = xv[2 * i + 1];
  s16x8 o;
  o[0] = f2h(a.x); o[1] = f2h(a.y); o[2] = f2h(a.z); o[3] = f2h(a.w);
  o[4] = f2h(b.x); o[5] = f2h(b.y); o[6] = f2h(b.z); o[7] = f2h(b.w);
  ((s16x8*)xb)[i] = o;
}

__global__ __launch_bounds__(256) void conv_w_kernel(const float* __restrict__ Wh,
                                                     const float* __restrict__ Wl,
                                                     const float* __restrict__ Wg,
                                                     const float* __restrict__ Wm,
                                                     short* __restrict__ Wt) {
  int idx = blockIdx.x * 256 + threadIdx.x;
  int k = idx & 511, n = (idx >> 9) & 511, w = idx >> 18;
  const float* W = (w == 0) ? Wh : (w == 1) ? Wl : (w == 2) ? Wg : Wm;
  Wt[idx] = f2h(W[k * 512 + n]);
}

// ---------------- fused 3-way MLP GEMM ----------------

__global__ __launch_bounds__(256) void mlp3_kernel(const short* __restrict__ A,
                                                   const short* __restrict__ Wt_all,
                                                   const float* __restrict__ bh,
                                                   const float* __restrict__ bl,
                                                   const float* __restrict__ bg,
                                                   short* __restrict__ h,
                                                   short* __restrict__ l,
                                                   short* __restrict__ gT) {
  int z = blockIdx.z;
  const short* Wt = Wt_all + z * 262144;
  const float* bias = (z == 0) ? bh : (z == 1) ? bl : bg;

  __shared__ __align__(16) short lds_a[128 * 40];
  __shared__ __align__(16) short lds_b[128 * 40];
  int tid = threadIdx.x, lane = tid & 63, w = tid >> 6;
  int wm = w >> 1, wn = w & 1;
  int bm = blockIdx.x * 128, bn = blockIdx.y * 128;

  f32x4 acc[4][4];
#pragma unroll
  for (int mi = 0; mi < 4; ++mi)
#pragma unroll
    for (int ni = 0; ni < 4; ++ni) acc[mi][ni] = (f32x4){0.f, 0.f, 0.f, 0.f};

  for (int k0 = 0; k0 < 512; k0 += 32) {
#pragma unroll
    for (int it = 0; it < 2; ++it) {
      int chunk = tid + it * 256;
      int row = chunk >> 2, c8 = (chunk & 3) * 8;
      *(s16x8*)&lds_a[row * 40 + c8] =
          *(const s16x8*)&A[(size_t)(bm + row) * 512 + k0 + c8];
      *(s16x8*)&lds_b[row * 40 + c8] =
          *(const s16x8*)&Wt[(bn + row) * 512 + k0 + c8];
    }
    __syncthreads();
    f16x8 af[4], bfr[4];
#pragma unroll
    for (int mi = 0; mi < 4; ++mi)
      af[mi] = *(const f16x8*)&lds_a[(wm * 64 + mi * 16 + (lane & 15)) * 40 +
                                     (lane >> 4) * 8];
#pragma unroll
    for (int ni = 0; ni < 4; ++ni)
      bfr[ni] = *(const f16x8*)&lds_b[(wn * 64 + ni * 16 + (lane & 15)) * 40 +
                                      (lane >> 4) * 8];
#pragma unroll
    for (int mi = 0; mi < 4; ++mi)
#pragma unroll
      for (int ni = 0; ni < 4; ++ni) acc[mi][ni] = MFMA(af[mi], bfr[ni], acc[mi][ni]);
    __syncthreads();
  }

#pragma unroll
  for (int mi = 0; mi < 4; ++mi)
#pragma unroll
    for (int ni = 0; ni < 4; ++ni) {
      int col = bn + wn * 64 + ni * 16 + (lane & 15);
      float bv = bias[col];
#pragma unroll
      for (int r = 0; r < 4; ++r) {
        int row = bm + wm * 64 + mi * 16 + (lane >> 4) * 4 + r;
        float v = fmaxf(acc[mi][ni][r] + bv, 0.0f);
        short o = f2h(v);
        if (z == 0) h[(size_t)row * 512 + col] = o;
        else if (z == 1) l[(size_t)row * 512 + col] = o;
        else {
          int bb = row >> 11, mm = row & 2047;
          gT[((size_t)bb * 512 + col) * 2048 + mm] = o;
        }
      }
    }
}

// ---------------- flash attention + residual ----------------
// grid: 512 blocks x 256 threads. Block: 32 queries; wave w: q-group (w>>1),
// D-half (w&1). Each wave-pair duplicates QK^T+softmax, splits PV by D.
// LDS: K[32][512+8] 33280B + G[512][32+8] 40960B + P[4][16][40] 5120B = 79360B
// -> 2 blocks/CU -> 2 waves/SIMD.

__global__ __launch_bounds__(256, 2) void attn_kernel(const short* __restrict__ lmat,
                                                      const short* __restrict__ hmat,
                                                      const short* __restrict__ gT,
                                                      const float* __restrict__ x,
                                                      short* __restrict__ y) {
  __shared__ __align__(16) short lds_k[32 * 520];
  __shared__ __align__(16) short lds_g[512 * 40];
  __shared__ __align__(16) short lds_p[4][16 * 40];
  int tid = threadIdx.x, lane = tid & 63, w = tid >> 6;
  // XCD-bijective swizzle: 512 blocks = 8 XCDs x 64; XCD j handles batch j.
  int swz = (blockIdx.x & 7) * 64 + (blockIdx.x >> 3);
  int b = swz >> 6, qt = swz & 63;
  int qg = w >> 1, dh = w & 1;
  int q0 = qt * 32 + qg * 16;
  int d0 = dh * 256;
  const short* lb = lmat + (size_t)b * 2048 * 512;
  const short* hb = hmat + (size_t)b * 2048 * 512;
  const short* gb = gT + (size_t)b * 512 * 2048;

  // Q fragments resident: full D (needed for QK^T): 16 x 8 fp16 = 64 VGPR
  f16x8 qf[16];
  {
    int q = q0 + (lane & 15);
#pragma unroll
    for (int ks = 0; ks < 16; ++ks)
      qf[ks] = *(const f16x8*)&lb[(size_t)q * 512 + ks * 32 + (lane >> 4) * 8];
  }
  f32x4 accO[16];  // D-half: 16 x 16-col frags
#pragma unroll
  for (int i = 0; i < 16; ++i) accO[i] = (f32x4){0.f, 0.f, 0.f, 0.f};
  float mrun[4], lsumL[4];  // lsumL: per-lane partial softmax denominator
#pragma unroll
  for (int r = 0; r < 4; ++r) { mrun[r] = -3e38f; lsumL[r] = 0.f; }

  for (int kt = 0; kt < 64; ++kt) {
    int key0 = kt * 32;
    // ---- cooperative stage: K tile [32][512] + G tile [512][32] ----
#pragma unroll
    for (int it = 0; it < 8; ++it) {
      int chunk = tid + it * 256;  // 2048 chunks of 8 halves
      int row = chunk >> 6, c8 = (chunk & 63) * 8;
      *(s16x8*)&lds_k[row * 520 + c8] =
          *(const s16x8*)&hb[(size_t)(key0 + row) * 512 + c8];
    }
#pragma unroll
    for (int it = 0; it < 8; ++it) {
      int chunk = tid + it * 256;
      int row = chunk >> 2, c8 = (chunk & 3) * 8;
      *(s16x8*)&lds_g[row * 40 + c8] =
          *(const s16x8*)&gb[(size_t)row * 2048 + key0 + c8];
    }
    __syncthreads();

    // ---- S = Q K^T (16 q x 32 keys) ----
    f32x4 s0 = {0.f, 0.f, 0.f, 0.f}, s1 = {0.f, 0.f, 0.f, 0.f};
#pragma unroll
    for (int ks = 0; ks < 16; ++ks) {
      f16x8 k0f = *(const f16x8*)&lds_k[(lane & 15) * 520 + ks * 32 + (lane >> 4) * 8];
      s0 = MFMA(qf[ks], k0f, s0);
      f16x8 k1f = *(const f16x8*)&lds_k[(16 + (lane & 15)) * 520 + ks * 32 + (lane >> 4) * 8];
      s1 = MFMA(qf[ks], k1f, s1);
    }

    // ---- online softmax, defer-max (THR=8), per-lane lsum partial ----
    float mnew[4];
    bool ok = true;
#pragma unroll
    for (int r = 0; r < 4; ++r) {
      float m2 = fmaxf(s0[r], s1[r]);
#pragma unroll
      for (int m = 1; m < 16; m <<= 1) m2 = fmaxf(m2, __shfl_xor(m2, m));
      mnew[r] = fmaxf(mrun[r], m2);
      ok = ok && (m2 <= mrun[r] + 8.0f);
    }
    if (!__all((int)ok)) {
      float sc[4];
#pragma unroll
      for (int r = 0; r < 4; ++r) {
        sc[r] = __expf(mrun[r] - mnew[r]);
        mrun[r] = mnew[r];
        lsumL[r] *= sc[r];
      }
#pragma unroll
      for (int nf = 0; nf < 16; ++nf) {
        accO[nf][0] *= sc[0]; accO[nf][1] *= sc[1];
        accO[nf][2] *= sc[2]; accO[nf][3] *= sc[3];
      }
    }
#pragma unroll
    for (int r = 0; r < 4; ++r) {
      float p0 = __expf(s0[r] - mrun[r]);  // bounded by e^8
      float p1 = __expf(s1[r] - mrun[r]);
      int qr = (lane >> 4) * 4 + r;
      lds_p[w][qr * 40 + (lane & 15)] = f2h(p0);
      lds_p[w][qr * 40 + 16 + (lane & 15)] = f2h(p1);
      lsumL[r] += p0 + p1;
    }

    // ---- PV for this wave's D-half ----
    f16x8 pa = *(const f16x8*)&lds_p[w][(lane & 15) * 40 + (lane >> 4) * 8];
#pragma unroll
    for (int nf = 0; nf < 16; ++nf) {
      f16x8 gf = *(const f16x8*)&lds_g[(d0 + nf * 16 + (lane & 15)) * 40 + (lane >> 4) * 8];
      accO[nf] = MFMA(pa, gf, accO[nf]);
    }
    __syncthreads();
  }

  // ---- epilogue: reduce lsum across 16-lane group, residual, store ----
  float lsum[4];
#pragma unroll
  for (int r = 0; r < 4; ++r) {
    float s = lsumL[r];
#pragma unroll
    for (int m = 1; m < 16; m <<= 1) s += __shfl_xor(s, m);
    lsum[r] = s;
  }
#pragma unroll
  for (int nf = 0; nf < 16; ++nf) {
    int c = d0 + nf * 16 + (lane & 15);
#pragma unroll
    for (int r = 0; r < 4; ++r) {
      int q = q0 + (lane >> 4) * 4 + r;
      float v = accO[nf][r] / lsum[r];
      v += x[((size_t)b * 2048 + q) * 512 + c];
      y[((size_t)b * 2048 + q) * 512 + c] = f2h(v);
    }
  }
}

// ---------------- final GEMM: relu(y @ Wm + bm) -> f32 out ----------------

__global__ __launch_bounds__(256) void final_gemm_kernel(const short* __restrict__ A,
                                                         const short* __restrict__ Wt,
                                                         const float* __restrict__ bias,
                                                         float* __restrict__ out) {
  __shared__ __align__(16) short lds_a[128 * 40];
  __shared__ __align__(16) short lds_b[128 * 40];
  int tid = threadIdx.x, lane = tid & 63, w = tid >> 6;
  int wm = w >> 1, wn = w & 1;
  int bm = blockIdx.x * 128, bn = blockIdx.y * 128;

  f32x4 acc[4][4];
#pragma unroll
  for (int mi = 0; mi < 4; ++mi)
#pragma unroll
    for (int ni = 0; ni < 4; ++ni) acc[mi][ni] = (f32x4){0.f, 0.f, 0.f, 0.f};

  for (int k0 = 0; k0 < 512; k0 += 32) {
#pragma unroll
    for (int it = 0; it < 2; ++it) {
      int chunk = tid + it * 256;
      int row = chunk >> 2, c8 = (chunk & 3) * 8;
      *(s16x8*)&lds_a[row * 40 + c8] =
          *(const s16x8*)&A[(size_t)(bm + row) * 512 + k0 + c8];
      *(s16x8*)&lds_b[row * 40 + c8] =
          *(const s16x8*)&Wt[(bn + row) * 512 + k0 + c8];
    }
    __syncthreads();
    f16x8 af[4], bfr[4];
#pragma unroll
    for (int mi = 0; mi < 4; ++mi)
      af[mi] = *(const f16x8*)&lds_a[(wm * 64 + mi * 16 + (lane & 15)) * 40 +
                                     (lane >> 4) * 8];
#pragma unroll
    for (int ni = 0; ni < 4; ++ni)
      bfr[ni] = *(const f16x8*)&lds_b[(wn * 64 + ni * 16 + (lane & 15)) * 40 +
                                      (lane >> 4) * 8];
#pragma unroll
    for (int mi = 0; mi < 4; ++mi)
#pragma unroll
      for (int ni = 0; ni < 4; ++ni) acc[mi][ni] = MFMA(af[mi], bfr[ni], acc[mi][ni]);
    __syncthreads();
  }

#pragma unroll
  for (int mi = 0; mi < 4; ++mi)
#pragma unroll
    for (int ni = 0; ni < 4; ++ni) {
      int col = bn + wn * 64 + ni * 16 + (lane & 15);
      float bv = bias[col];
#pragma unroll
      for (int r = 0; r < 4; ++r) {
        int row = bm + wm * 64 + mi * 16 + (lane >> 4) * 4 + r;
        out[(size_t)row * 512 + col] = fmaxf(acc[mi][ni][r] + bv, 0.0f);
      }
    }
}

// ---------------- host launch ----------------

extern "C" void kernel_launch(void* const* d_in, const int* in_sizes, int n_in,
                              void* d_out, int out_size, void* d_ws, size_t ws_size,
                              hipStream_t stream) {
  const float* x  = (const float*)d_in[0];
  const float* Wh = (const float*)d_in[1];
  const float* bh = (const float*)d_in[2];
  const float* Wl = (const float*)d_in[3];
  const float* bl = (const float*)d_in[4];
  const float* Wg = (const float*)d_in[5];
  const float* bg = (const float*)d_in[6];
  const float* Wm = (const float*)d_in[7];
  const float* bm = (const float*)d_in[8];

  char* ws = (char*)d_ws;
  const size_t SZ = 16777216;
  short* xb  = (short*)(ws + 0 * SZ);
  short* h   = (short*)(ws + 1 * SZ);
  short* l   = (short*)(ws + 2 * SZ);
  short* gT  = (short*)(ws + 3 * SZ);
  short* y   = (short*)(ws + 4 * SZ);
  short* Wt  = (short*)(ws + 5 * SZ);

  conv_x_kernel<<<4096, 256, 0, stream>>>(x, xb);
  conv_w_kernel<<<4096, 256, 0, stream>>>(Wh, Wl, Wg, Wm, Wt);
  mlp3_kernel<<<dim3(128, 4, 3), 256, 0, stream>>>(xb, Wt, bh, bl, bg, h, l, gT);
  attn_kernel<<<512, 256, 0, stream>>>(l, h, gT, x, y);
  final_gemm_kernel<<<dim3(128, 4), 256, 0, stream>>>(y, Wt + 3 * 262144, bm,
                                                      (float*)d_out);
}

// Round 4
// 285.899 us; speedup vs baseline: 1.6327x; 1.6327x over previous
//
#include <hip/hip_runtime.h>

// B=8, N=2048, C=512. Flash attention + fp16 MFMA pipeline.
// attn r4: 2-phase double-buffered pipeline, global_load_lds staging,
// XOR-swizzled K tile (linear dest + inverse-swizzled source + swizzled read),
// 1 barrier/key-tile, 4 waves x 16q full-D, defer-max, XCD-bijective swizzle.
// ws layout: xb(16MB) h(16MB) l(16MB) gT(16MB) y(16MB) Wt(2MB)  [fp16 bits in short]

typedef __attribute__((ext_vector_type(4))) float f32x4;
typedef __attribute__((ext_vector_type(8))) short s16x8;      // fp16 bit-patterns
typedef __attribute__((ext_vector_type(8))) _Float16 f16x8;   // MFMA operand

typedef unsigned int u32;
typedef __attribute__((address_space(1))) const u32 gu32;
typedef __attribute__((address_space(3))) u32 lu32;

__device__ __forceinline__ void gload16(const short* g, short* l) {
  // async global->LDS, 16B/lane; LDS dest = wave-uniform base + lane*16.
  __builtin_amdgcn_global_load_lds((gu32*)g, (lu32*)l, 16, 0, 0);
}

__device__ __forceinline__ short f2h(float f) {
  _Float16 h = (_Float16)f;  // v_cvt_f16_f32, RTN
  return __builtin_bit_cast(short, h);
}

#define MFMA(a, b, c) __builtin_amdgcn_mfma_f32_16x16x32_f16(a, b, c, 0, 0, 0)

// ---------------- conversion kernels ----------------

__global__ __launch_bounds__(256) void conv_x_kernel(const float* __restrict__ x,
                                                     short* __restrict__ xb) {
  int i = blockIdx.x * 256 + threadIdx.x;
  const float4* xv = (const float4*)x;
  float4 a = xv[2 * i], b = xv[2 * i + 1];
  s16x8 o;
  o[0] = f2h(a.x); o[1] = f2h(a.y); o[2] = f2h(a.z); o[3] = f2h(a.w);
  o[4] = f2h(b.x); o[5] = f2h(b.y); o[6] = f2h(b.z); o[7] = f2h(b.w);
  ((s16x8*)xb)[i] = o;
}

__global__ __launch_bounds__(256) void conv_w_kernel(const float* __restrict__ Wh,
                                                     const float* __restrict__ Wl,
                                                     const float* __restrict__ Wg,
                                                     const float* __restrict__ Wm,
                                                     short* __restrict__ Wt) {
  int idx = blockIdx.x * 256 + threadIdx.x;
  int k = idx & 511, n = (idx >> 9) & 511, w = idx >> 18;
  const float* W = (w == 0) ? Wh : (w == 1) ? Wl : (w == 2) ? Wg : Wm;
  Wt[idx] = f2h(W[k * 512 + n]);
}

// ---------------- fused 3-way MLP GEMM ----------------

__global__ __launch_bounds__(256) void mlp3_kernel(const short* __restrict__ A,
                                                   const short* __restrict__ Wt_all,
                                                   const float* __restrict__ bh,
                                                   const float* __restrict__ bl,
                                                   const float* __restrict__ bg,
                                                   short* __restrict__ h,
                                                   short* __restrict__ l,
                                                   short* __restrict__ gT) {
  int z = blockIdx.z;
  const short* Wt = Wt_all + z * 262144;
  const float* bias = (z == 0) ? bh : (z == 1) ? bl : bg;

  __shared__ __align__(16) short lds_a[128 * 40];
  __shared__ __align__(16) short lds_b[128 * 40];
  int tid = threadIdx.x, lane = tid & 63, w = tid >> 6;
  int wm = w >> 1, wn = w & 1;
  int bm = blockIdx.x * 128, bn = blockIdx.y * 128;

  f32x4 acc[4][4];
#pragma unroll
  for (int mi = 0; mi < 4; ++mi)
#pragma unroll
    for (int ni = 0; ni < 4; ++ni) acc[mi][ni] = (f32x4){0.f, 0.f, 0.f, 0.f};

  for (int k0 = 0; k0 < 512; k0 += 32) {
#pragma unroll
    for (int it = 0; it < 2; ++it) {
      int chunk = tid + it * 256;
      int row = chunk >> 2, c8 = (chunk & 3) * 8;
      *(s16x8*)&lds_a[row * 40 + c8] =
          *(const s16x8*)&A[(size_t)(bm + row) * 512 + k0 + c8];
      *(s16x8*)&lds_b[row * 40 + c8] =
          *(const s16x8*)&Wt[(bn + row) * 512 + k0 + c8];
    }
    __syncthreads();
    f16x8 af[4], bfr[4];
#pragma unroll
    for (int mi = 0; mi < 4; ++mi)
      af[mi] = *(const f16x8*)&lds_a[(wm * 64 + mi * 16 + (lane & 15)) * 40 +
                                     (lane >> 4) * 8];
#pragma unroll
    for (int ni = 0; ni < 4; ++ni)
      bfr[ni] = *(const f16x8*)&lds_b[(wn * 64 + ni * 16 + (lane & 15)) * 40 +
                                      (lane >> 4) * 8];
#pragma unroll
    for (int mi = 0; mi < 4; ++mi)
#pragma unroll
      for (int ni = 0; ni < 4; ++ni) acc[mi][ni] = MFMA(af[mi], bfr[ni], acc[mi][ni]);
    __syncthreads();
  }

#pragma unroll
  for (int mi = 0; mi < 4; ++mi)
#pragma unroll
    for (int ni = 0; ni < 4; ++ni) {
      int col = bn + wn * 64 + ni * 16 + (lane & 15);
      float bv = bias[col];
#pragma unroll
      for (int r = 0; r < 4; ++r) {
        int row = bm + wm * 64 + mi * 16 + (lane >> 4) * 4 + r;
        float v = fmaxf(acc[mi][ni][r] + bv, 0.0f);
        short o = f2h(v);
        if (z == 0) h[(size_t)row * 512 + col] = o;
        else if (z == 1) l[(size_t)row * 512 + col] = o;
        else {
          int bb = row >> 11, mm = row & 2047;
          gT[((size_t)bb * 512 + col) * 2048 + mm] = o;
        }
      }
    }
}

// ---------------- flash attention + residual ----------------
// 256 blocks x 256 threads (4 waves x 16 q, full D). KVBLK=32, double-buffered
// K[32][512] (XOR-swizzled) + G[512][32] (linear) staged via global_load_lds.
// LDS: 2*32KB (K) + 2*32KB (G) + 4*1KB (P) = 136KB -> 1 block/CU.

__global__ __launch_bounds__(256, 1) void attn_kernel(const short* __restrict__ lmat,
                                                      const short* __restrict__ hmat,
                                                      const short* __restrict__ gT,
                                                      const float* __restrict__ x,
                                                      short* __restrict__ y) {
  __shared__ __align__(16) short kbuf[2][16384];  // [32 keys][512], rows XOR-swizzled
  __shared__ __align__(16) short gbuf[2][16384];  // [512 c][32 keys], linear
  __shared__ __align__(16) short lds_p[4][512];   // per-wave P [16 q][32 keys]
  int tid = threadIdx.x, lane = tid & 63, w = tid >> 6;
  // XCD-bijective: 256 blocks = 8 XCDs x 32; XCD j handles batch j.
  int swz = (blockIdx.x & 7) * 32 + (blockIdx.x >> 3);
  int b = swz >> 5, qt = swz & 31;
  int q0 = qt * 64 + w * 16;
  const short* lb = lmat + (size_t)b * 2048 * 512;
  const short* hb = hmat + (size_t)b * 2048 * 512;
  const short* gb = gT + (size_t)b * 512 * 2048;

  int r0 = lane & 15, g = lane >> 4;

  // Q fragments resident: 16 k-steps x 8 fp16 = 64 VGPR
  f16x8 qf[16];
  {
    int q = q0 + r0;
#pragma unroll
    for (int ks = 0; ks < 16; ++ks)
      qf[ks] = *(const f16x8*)&lb[(size_t)q * 512 + ks * 32 + g * 8];
  }
  f32x4 accO[32];
#pragma unroll
  for (int i = 0; i < 32; ++i) accO[i] = (f32x4){0.f, 0.f, 0.f, 0.f};
  float mrun[4], lsumL[4];
#pragma unroll
  for (int r = 0; r < 4; ++r) { mrun[r] = -3e38f; lsumL[r] = 0.f; }

  // ---- staging: 16 global_load_lds per thread per tile ----
  // K chunk wl (0..31) = key row wl: linear LDS row, source column inverse-swizzled.
  // G chunk wl = gT rows [wl*16, wl*16+16) x 32 keys, fully linear.
  auto stage = [&](int buf, int t) {
    int key0 = t * 32;
    short* kd = &kbuf[buf][0];
    short* gd = &gbuf[buf][0];
#pragma unroll
    for (int j = 0; j < 8; ++j) {
      int wl = w * 8 + j;
      gload16(hb + (size_t)(key0 + wl) * 512 + (((lane * 16) ^ ((wl & 7) << 4)) >> 1),
              kd + wl * 512);
      int c = wl * 16 + (lane >> 2);
      gload16(gb + (size_t)c * 2048 + key0 + (lane & 3) * 8,
              gd + wl * 512);
    }
  };

  stage(0, 0);
  __syncthreads();
  int cur = 0;

  for (int kt = 0; kt < 64; ++kt) {
    if (kt < 63) stage(cur ^ 1, kt + 1);  // loads fly during compute below

    const short* kb = &kbuf[cur][0];
    const short* gp = &gbuf[cur][0];

    // ---- S = Q K^T (16 q x 32 keys), swizzled K reads ----
    f32x4 s0 = {0.f, 0.f, 0.f, 0.f}, s1 = {0.f, 0.f, 0.f, 0.f};
#pragma unroll
    for (int ks = 0; ks < 16; ++ks) {
      f16x8 k0f = *(const f16x8*)&kb[(r0 * 512 + ks * 32 + g * 8) ^ ((r0 & 7) << 3)];
      s0 = MFMA(qf[ks], k0f, s0);
      f16x8 k1f = *(const f16x8*)&kb[((r0 + 16) * 512 + ks * 32 + g * 8) ^ ((r0 & 7) << 3)];
      s1 = MFMA(qf[ks], k1f, s1);
    }

    // ---- online softmax, defer-max (THR=8), per-lane lsum partials ----
    float mnew[4];
    bool ok = true;
#pragma unroll
    for (int r = 0; r < 4; ++r) {
      float m2 = fmaxf(s0[r], s1[r]);
#pragma unroll
      for (int m = 1; m < 16; m <<= 1) m2 = fmaxf(m2, __shfl_xor(m2, m));
      mnew[r] = fmaxf(mrun[r], m2);
      ok = ok && (m2 <= mrun[r] + 8.0f);
    }
    if (!__all((int)ok)) {
      float sc[4];
#pragma unroll
      for (int r = 0; r < 4; ++r) {
        sc[r] = __expf(mrun[r] - mnew[r]);
        mrun[r] = mnew[r];
        lsumL[r] *= sc[r];
      }
#pragma unroll
      for (int nf = 0; nf < 32; ++nf) {
        accO[nf][0] *= sc[0]; accO[nf][1] *= sc[1];
        accO[nf][2] *= sc[2]; accO[nf][3] *= sc[3];
      }
    }
#pragma unroll
    for (int r = 0; r < 4; ++r) {
      float p0 = __expf(s0[r] - mrun[r]);  // bounded by e^8
      float p1 = __expf(s1[r] - mrun[r]);
      int qr = g * 4 + r;
      lds_p[w][qr * 32 + r0] = f2h(p0);
      lds_p[w][qr * 32 + 16 + r0] = f2h(p1);
      lsumL[r] += p0 + p1;
    }

    // ---- PV, full D (32 frags) ----
    f16x8 pa = *(const f16x8*)&lds_p[w][r0 * 32 + g * 8];
#pragma unroll
    for (int nf = 0; nf < 32; ++nf) {
      f16x8 gf = *(const f16x8*)&gp[(nf * 16 + r0) * 32 + g * 8];
      accO[nf] = MFMA(pa, gf, accO[nf]);
    }

    __syncthreads();  // next-tile staging landed; all waves done with buf[cur]
    cur ^= 1;
  }

  // ---- epilogue: reduce lsum across 16-lane group, residual, store ----
  float lsum[4];
#pragma unroll
  for (int r = 0; r < 4; ++r) {
    float s = lsumL[r];
#pragma unroll
    for (int m = 1; m < 16; m <<= 1) s += __shfl_xor(s, m);
    lsum[r] = s;
  }
#pragma unroll
  for (int nf = 0; nf < 32; ++nf) {
    int c = nf * 16 + r0;
#pragma unroll
    for (int r = 0; r < 4; ++r) {
      int q = q0 + g * 4 + r;
      float v = accO[nf][r] / lsum[r];
      v += x[((size_t)b * 2048 + q) * 512 + c];
      y[((size_t)b * 2048 + q) * 512 + c] = f2h(v);
    }
  }
}

// ---------------- final GEMM: relu(y @ Wm + bm) -> f32 out ----------------

__global__ __launch_bounds__(256) void final_gemm_kernel(const short* __restrict__ A,
                                                         const short* __restrict__ Wt,
                                                         const float* __restrict__ bias,
                                                         float* __restrict__ out) {
  __shared__ __align__(16) short lds_a[128 * 40];
  __shared__ __align__(16) short lds_b[128 * 40];
  int tid = threadIdx.x, lane = tid & 63, w = tid >> 6;
  int wm = w >> 1, wn = w & 1;
  int bm = blockIdx.x * 128, bn = blockIdx.y * 128;

  f32x4 acc[4][4];
#pragma unroll
  for (int mi = 0; mi < 4; ++mi)
#pragma unroll
    for (int ni = 0; ni < 4; ++ni) acc[mi][ni] = (f32x4){0.f, 0.f, 0.f, 0.f};

  for (int k0 = 0; k0 < 512; k0 += 32) {
#pragma unroll
    for (int it = 0; it < 2; ++it) {
      int chunk = tid + it * 256;
      int row = chunk >> 2, c8 = (chunk & 3) * 8;
      *(s16x8*)&lds_a[row * 40 + c8] =
          *(const s16x8*)&A[(size_t)(bm + row) * 512 + k0 + c8];
      *(s16x8*)&lds_b[row * 40 + c8] =
          *(const s16x8*)&Wt[(bn + row) * 512 + k0 + c8];
    }
    __syncthreads();
    f16x8 af[4], bfr[4];
#pragma unroll
    for (int mi = 0; mi < 4; ++mi)
      af[mi] = *(const f16x8*)&lds_a[(wm * 64 + mi * 16 + (lane & 15)) * 40 +
                                     (lane >> 4) * 8];
#pragma unroll
    for (int ni = 0; ni < 4; ++ni)
      bfr[ni] = *(const f16x8*)&lds_b[(wn * 64 + ni * 16 + (lane & 15)) * 40 +
                                      (lane >> 4) * 8];
#pragma unroll
    for (int mi = 0; mi < 4; ++mi)
#pragma unroll
      for (int ni = 0; ni < 4; ++ni) acc[mi][ni] = MFMA(af[mi], bfr[ni], acc[mi][ni]);
    __syncthreads();
  }

#pragma unroll
  for (int mi = 0; mi < 4; ++mi)
#pragma unroll
    for (int ni = 0; ni < 4; ++ni) {
      int col = bn + wn * 64 + ni * 16 + (lane & 15);
      float bv = bias[col];
#pragma unroll
      for (int r = 0; r < 4; ++r) {
        int row = bm + wm * 64 + mi * 16 + (lane >> 4) * 4 + r;
        out[(size_t)row * 512 + col] = fmaxf(acc[mi][ni][r] + bv, 0.0f);
      }
    }
}

// ---------------- host launch ----------------

extern "C" void kernel_launch(void* const* d_in, const int* in_sizes, int n_in,
                              void* d_out, int out_size, void* d_ws, size_t ws_size,
                              hipStream_t stream) {
  const float* x  = (const float*)d_in[0];
  const float* Wh = (const float*)d_in[1];
  const float* bh = (const float*)d_in[2];
  const float* Wl = (const float*)d_in[3];
  const float* bl = (const float*)d_in[4];
  const float* Wg = (const float*)d_in[5];
  const float* bg = (const float*)d_in[6];
  const float* Wm = (const float*)d_in[7];
  const float* bm = (const float*)d_in[8];

  char* ws = (char*)d_ws;
  const size_t SZ = 16777216;
  short* xb  = (short*)(ws + 0 * SZ);
  short* h   = (short*)(ws + 1 * SZ);
  short* l   = (short*)(ws + 2 * SZ);
  short* gT  = (short*)(ws + 3 * SZ);
  short* y   = (short*)(ws + 4 * SZ);
  short* Wt  = (short*)(ws + 5 * SZ);

  conv_x_kernel<<<4096, 256, 0, stream>>>(x, xb);
  conv_w_kernel<<<4096, 256, 0, stream>>>(Wh, Wl, Wg, Wm, Wt);
  mlp3_kernel<<<dim3(128, 4, 3), 256, 0, stream>>>(xb, Wt, bh, bl, bg, h, l, gT);
  attn_kernel<<<256, 256, 0, stream>>>(l, h, gT, x, y);
  final_gemm_kernel<<<dim3(128, 4), 256, 0, stream>>>(y, Wt + 3 * 262144, bm,
                                                      (float*)d_out);
}